// Round 14
// baseline (150.568 us; speedup 1.0000x reference)
//
#include <hip/hip_runtime.h>
#include <hip/hip_bf16.h>

// DenseAttention — reassociated (6.44 GF vs 155 GF direct), bf16 MFMA.
// Round 14: r13 chain (best, 138.1us) + occupancy/pipelining middle point.
// r10 (8 syncs, 16KB LDS, 4 blk/CU) = 147.7; r12/13 (1 sync, 64KB, 2 blk/CU)
// = 140/138. Untested middle: TWO K=128 bursts (16KB/operand -> 32KB/block ->
// 4-5 blk/CU, 3 syncs) — enough residency that one block's MFMA hides
// another's staging burst (m114 co-scheduling).
//   gram:  Gp[s][bq][f][h] = x_f . x_h     grid(16,8,8)=1024, non-atomic,
//          + zeroes Wt slices (no memset dispatch)
//   2a:    Tt[ba][g][qf] = comb_g . (sum_s Gp)_f  grid(16,32)=512, bf16 out
//   2b:    Wt[ba][g][e] += Tt_g . qw_e     grid(16,8,4)=512, split-K4, atomic
//   out:   out[t][ag]   = x_t . Wt_g       grid(128,8)=1024
// Fragment-major LDS -> conflict-free ds_read_b128 fragment reads.
// ws (22 MB): Gp 16 | Wt 2 | Tt(bf16) 4.

typedef unsigned short u16;
using short8  = __attribute__((ext_vector_type(8))) short;
using floatx4 = __attribute__((ext_vector_type(4))) float;

__device__ inline u16 f2bf(float f) {               // RNE f32->bf16
    unsigned u = __float_as_uint(f);
    unsigned r = u + 0x7fffu + ((u >> 16) & 1u);
    return (u16)(r >> 16);
}

// Row-major source [64 m][64 k] (k-contiguous) -> fragment-major LDS (MT=4).
// Element (m,k): lane=((k&31)>>3)*16+(m&15), j=k&7,
// chunk=((k>>5)*4+(m>>4))*64+lane.  dst = one 4096-u16 fragment block.
template <typename T>
__device__ inline void stage64(const T* __restrict__ src, long ld,
                               u16* __restrict__ dst, int tid) {
#pragma unroll
    for (int it = 0; it < 4; ++it) {
        const int flat = (it * 256 + tid) * 4;
        const int kl = flat & 63, rl = flat >> 6;
        ushort4 v;
        if (sizeof(T) == 4) {
            const float4 f = *(const float4*)&((const float*)src)[(long)rl * ld + kl];
            v.x = f2bf(f.x); v.y = f2bf(f.y); v.z = f2bf(f.z); v.w = f2bf(f.w);
        } else {
            v = *(const ushort4*)&((const u16*)src)[(long)rl * ld + kl];
        }
        const int chunk = ((kl >> 5) * 4 + (rl >> 4)) * 64 + ((kl >> 3) & 3) * 16 + (rl & 15);
        *(ushort4*)&dst[chunk * 8 + (kl & 7)] = v;
    }
}

// Same, but source = f32 sum of 8 partial arrays spaced partStride apart.
__device__ inline void stage64_sum8(const float* __restrict__ s0, long ld,
                                    long partStride,
                                    u16* __restrict__ dst, int tid) {
#pragma unroll
    for (int it = 0; it < 4; ++it) {
        const int flat = (it * 256 + tid) * 4;
        const int kl = flat & 63, rl = flat >> 6;
        const long off = (long)rl * ld + kl;
        float4 acc = *(const float4*)&s0[off];
#pragma unroll
        for (int s = 1; s < 8; ++s) {
            const float4 f = *(const float4*)&s0[(long)s * partStride + off];
            acc.x += f.x; acc.y += f.y; acc.z += f.z; acc.w += f.w;
        }
        ushort4 v;
        v.x = f2bf(acc.x); v.y = f2bf(acc.y); v.z = f2bf(acc.z); v.w = f2bf(acc.w);
        const int chunk = ((kl >> 5) * 4 + (rl >> 4)) * 64 + ((kl >> 3) & 3) * 16 + (rl & 15);
        *(ushort4*)&dst[chunk * 8 + (kl & 7)] = v;
    }
}

// K-major f32 source [64 k][64 m] (m-contiguous, row stride ld) -> fragment-
// major LDS (scatter writes; round-6/10/12-verified pattern).
__device__ inline void stage_km64(const float* __restrict__ src, long ld,
                                  u16* __restrict__ dst, int tid) {
#pragma unroll
    for (int it = 0; it < 4; ++it) {
        const int flat = (it * 256 + tid) * 4;
        const int m = flat & 63, k = flat >> 6;
        const float4 f = *(const float4*)&src[(long)k * ld + m];
        const int cb_ = ((k >> 5) * 4 + (m >> 4)) * 64 + ((k & 31) >> 3) * 16 + (m & 15);
        const int j = k & 7;
        dst[(cb_ + 0) * 8 + j] = f2bf(f.x);
        dst[(cb_ + 1) * 8 + j] = f2bf(f.y);
        dst[(cb_ + 2) * 8 + j] = f2bf(f.z);
        dst[(cb_ + 3) * 8 + j] = f2bf(f.w);
    }
}

// C[m0+..64, n0+..64] (+)= A . B^T, K=256 as TWO 128-k bursts (16KB/operand,
// 3 syncs). 4 waves, wave w -> 32x32 at (IA=(w&1)*2, JB=(w>>1)*2) 16-tiles.
// AKM/BKM: operand from K-major f32. BSUM8: B = f32 sum of 8 partials.
// TC: float (plain or atomic) or u16 (bf16 store, non-atomic only).
template <typename TA, typename TB, typename TC,
          bool AKM, bool BKM, bool BSUM8, bool ATOMIC>
__device__ inline void gemm_tile(const TA* __restrict__ A, long lda,
                                 const TB* __restrict__ B, long ldb,
                                 long partStride,
                                 TC* __restrict__ C, long ldc,
                                 int m0, int n0) {
    __shared__ u16 As[8192];   // 16 KB: 2 x 64-k fragment blocks
    __shared__ u16 Bs[8192];
    const int tid = threadIdx.x, lane = tid & 63, w = tid >> 6;
    const int IA = (w & 1) * 2, JB = (w >> 1) * 2;
    floatx4 acc[2][2] = {};

#pragma unroll
    for (int burst = 0; burst < 2; ++burst) {
        if (burst) __syncthreads();          // protect LDS before restage
#pragma unroll
        for (int kb = 0; kb < 2; ++kb) {
            const int kk = burst * 128 + kb * 64;
            if (AKM) stage_km64((const float*)A + (long)kk * lda, lda, As + kb * 4096, tid);
            else     stage64(A + kk, lda, As + kb * 4096, tid);
            if (BSUM8)    stage64_sum8((const float*)B + kk, ldb, partStride, Bs + kb * 4096, tid);
            else if (BKM) stage_km64((const float*)B + (long)kk * ldb, ldb, Bs + kb * 4096, tid);
            else          stage64(B + kk, ldb, Bs + kb * 4096, tid);
        }
        __syncthreads();
#pragma unroll
        for (int kb = 0; kb < 2; ++kb)
#pragma unroll
            for (int s = 0; s < 2; ++s) {
                short8 af[2], bfr[2];
#pragma unroll
                for (int i = 0; i < 2; ++i)
                    af[i] = *(const short8*)&As[kb * 4096 + ((s * 4 + IA + i) * 64 + lane) * 8];
#pragma unroll
                for (int j = 0; j < 2; ++j)
                    bfr[j] = *(const short8*)&Bs[kb * 4096 + ((s * 4 + JB + j) * 64 + lane) * 8];
#pragma unroll
                for (int i = 0; i < 2; ++i)
#pragma unroll
                    for (int j = 0; j < 2; ++j)
                        acc[i][j] = __builtin_amdgcn_mfma_f32_16x16x32_bf16(af[i], bfr[j], acc[i][j], 0, 0, 0);
            }
    }

    const int rb = (lane >> 4) * 4, col = lane & 15;
#pragma unroll
    for (int i = 0; i < 2; ++i)
#pragma unroll
        for (int j = 0; j < 2; ++j)
#pragma unroll
            for (int r = 0; r < 4; ++r) {
                const int gm = m0 + (IA + i) * 16 + rb + r;
                const int gn = n0 + (JB + j) * 16 + col;
                TC* p = &C[(long)gm * ldc + gn];
                if (sizeof(TC) == 2) *(u16*)p = f2bf(acc[i][j][r]);
                else if (ATOMIC) atomicAdd((float*)p, acc[i][j][r]);
                else *(float*)p = acc[i][j][r];
            }
}

// gram: Gp[split][bq][f][h] = sum_{u in split} x[b][u][qf] * x[b][u][qh]
// (non-atomic; each block also zeroes its 2KB slice of Wt — consumed two
//  kernels later, stream order guarantees completion/visibility)
__global__ __launch_bounds__(256) void k_gram(const float* __restrict__ x,
                                              float* __restrict__ Gp,
                                              float* __restrict__ Wt) {
    const int tile = blockIdx.x, bq = blockIdx.y, split = blockIdx.z;
    const int tm = tile >> 2, tn = tile & 3;
    const int b = bq >> 2, q = bq & 3;
    {   // zero Wt: 1024 blocks x 512 floats (= 2 MB total)
        const int bl = tile + 16 * bq + 128 * split;
        if (threadIdx.x < 128) {
            const float4 zero = {0.f, 0.f, 0.f, 0.f};
            ((float4*)(Wt + (long)bl * 512))[threadIdx.x] = zero;
        }
    }
    const float* base = x + (long)b * 2097152 + (long)split * 256 * 1024 + q * 256;
    gemm_tile<float, float, float, true, true, false, false>(
        base + tm * 64, 1024,
        base + tn * 64, 1024, 0,
        Gp + (long)(split * 8 + bq) * 65536, 256,
        tm * 64, tn * 64);
}

// 2a: Tt[ba][g][q*256+f] = sum_h comb[a][q*256+h][g] * (sum_s Gp[s][bq])[f][h]
__global__ __launch_bounds__(256) void k_2a(const float* __restrict__ comb,
                                            const float* __restrict__ Gp,
                                            u16* __restrict__ Tt) {
    const int tile = blockIdx.x, i = blockIdx.y;     // i = ba*4+q
    const int tm = tile >> 2, tn = tile & 3;
    const int q = i & 3, ba = i >> 2, b = ba >> 2, a = ba & 3;
    gemm_tile<float, float, u16, true, false, true, false>(
        comb + (long)a * 262144 + (long)q * 256 * 256 + tm * 64, 256,
        Gp + (long)(b * 4 + q) * 65536 + (long)tn * 64 * 256, 256,
        (long)8 * 65536,
        Tt + (long)ba * 262144, 1024,
        tm * 64, q * 256 + tn * 64);
}

// 2b: Wt[ba][g][e] += sum_{k in split} Tt[ba][g][k] * qw[a][e][k]
__global__ __launch_bounds__(256) void k_2b(const u16* __restrict__ Tt,
                                            const float* __restrict__ qw,
                                            float* __restrict__ Wt) {
    const int tile = blockIdx.x, ba = blockIdx.y, split = blockIdx.z;
    const int tm = tile >> 2, tn = tile & 3;
    const int a = ba & 3;
    gemm_tile<u16, float, float, false, false, false, true>(
        Tt + (long)ba * 262144 + (long)tm * 64 * 1024 + split * 256, 1024,
        qw + (long)a * 262144 + (long)tn * 64 * 1024 + split * 256, 1024, 0,
        Wt + (long)ba * 65536, 256,
        tm * 64, tn * 64);
}

// out: out[b][t][a*256+g] = sum_e x[b][t][a*256+e] * Wt[ba][g][e]
__global__ __launch_bounds__(256) void k_3(const float* __restrict__ x,
                                           const float* __restrict__ Wt,
                                           float* __restrict__ out) {
    const int tl = blockIdx.x, ba = blockIdx.y;      // tl: tm 0..31, tn 0..3
    const int tm = tl >> 2, tn = tl & 3;
    const int b = ba >> 2, a = ba & 3;
    gemm_tile<float, float, float, false, false, false, false>(
        x + (long)b * 2097152 + (long)tm * 64 * 1024 + a * 256, 1024,
        Wt + (long)ba * 65536 + (long)tn * 64 * 256, 256, 0,
        out + (long)b * 2097152 + a * 256, 1024,
        tm * 64, tn * 64);
}

extern "C" void kernel_launch(void* const* d_in, const int* in_sizes, int n_in,
                              void* d_out, int out_size, void* d_ws, size_t ws_size,
                              hipStream_t stream) {
    const float* x    = (const float*)d_in[0];   // [2,2048,1024]
    const float* qw   = (const float*)d_in[1];   // [4,256,1024]
    const float* comb = (const float*)d_in[2];   // [4,1024,256]
    float* out = (float*)d_out;

    char* ws = (char*)d_ws;
    float* Gp = (float*)(ws);                    // 16 MB [8 split][8 bq][256x256]
    float* Wt = (float*)(ws + (16u << 20));      // 2 MB  [8][256][256]  Wt[g][e]
    u16*   Tt = (u16*)  (ws + (18u << 20));      // 4 MB  [8][256][1024] Tt[g][qf] bf16

    k_gram<<<dim3(16, 8, 8), 256, 0, stream>>>(x, Gp, Wt);
    k_2a  <<<dim3(16, 32),   256, 0, stream>>>(comb, Gp, Tt);
    k_2b  <<<dim3(16, 8, 4), 256, 0, stream>>>(Tt, qw, Wt);
    k_3   <<<dim3(128, 8),   256, 0, stream>>>(x, Wt, out);
}

// Round 15
// 137.096 us; speedup vs baseline: 1.0983x; 1.0983x over previous
//
#include <hip/hip_runtime.h>
#include <hip/hip_bf16.h>

// DenseAttention — reassociated (6.44 GF vs 155 GF direct), bf16 MFMA.
// Round 15: r13 chain (best, 138.1us) with gram upgraded to 128x128 tiles.
// Gram was the largest body term: 64-tiles re-read x 8x in f32 (128 MB).
// 128-tiles (4 waves x 64x64, r4/r7-verified 128-row fragment layout) halve
// re-reads -> 64 MB. Two K=128 bursts (32KB/operand; only fit for 128-tiles),
// each feeding 64 MFMA/wave — 4x the work-per-sync of r14's failed bursts.
//   gram:  Gp[s][bq][f][h] = x_f . x_h     grid(4,8,8)=256, 128-tiles,
//          non-atomic + zeroes Wt slices (no memset dispatch)
//   2a:    Tt[ba][g][qf] = comb_g . (sum_s Gp)_f  grid(16,32)=512, bf16 out
//   2b:    Wt[ba][g][e] += Tt_g . qw_e     grid(16,8,4)=512, split-K4, atomic
//   out:   out[t][ag]   = x_t . Wt_g       grid(128,8)=1024
// Fragment-major LDS -> conflict-free ds_read_b128 fragment reads.
// ws (22 MB): Gp 16 | Wt 2 | Tt(bf16) 4.

typedef unsigned short u16;
using short8  = __attribute__((ext_vector_type(8))) short;
using floatx4 = __attribute__((ext_vector_type(4))) float;

__device__ inline u16 f2bf(float f) {               // RNE f32->bf16
    unsigned u = __float_as_uint(f);
    unsigned r = u + 0x7fffu + ((u >> 16) & 1u);
    return (u16)(r >> 16);
}

// ---------------- 64-row stagers (2a/2b/out bodies — r13-verbatim) ----------
// Row-major source [64 m][64 k] -> fragment-major LDS (MT=4).
template <typename T>
__device__ inline void stage64(const T* __restrict__ src, long ld,
                               u16* __restrict__ dst, int tid) {
#pragma unroll
    for (int it = 0; it < 4; ++it) {
        const int flat = (it * 256 + tid) * 4;
        const int kl = flat & 63, rl = flat >> 6;
        ushort4 v;
        if (sizeof(T) == 4) {
            const float4 f = *(const float4*)&((const float*)src)[(long)rl * ld + kl];
            v.x = f2bf(f.x); v.y = f2bf(f.y); v.z = f2bf(f.z); v.w = f2bf(f.w);
        } else {
            v = *(const ushort4*)&((const u16*)src)[(long)rl * ld + kl];
        }
        const int chunk = ((kl >> 5) * 4 + (rl >> 4)) * 64 + ((kl >> 3) & 3) * 16 + (rl & 15);
        *(ushort4*)&dst[chunk * 8 + (kl & 7)] = v;
    }
}

// Same, source = f32 sum of 8 partial arrays spaced partStride apart.
__device__ inline void stage64_sum8(const float* __restrict__ s0, long ld,
                                    long partStride,
                                    u16* __restrict__ dst, int tid) {
#pragma unroll
    for (int it = 0; it < 4; ++it) {
        const int flat = (it * 256 + tid) * 4;
        const int kl = flat & 63, rl = flat >> 6;
        const long off = (long)rl * ld + kl;
        float4 acc = *(const float4*)&s0[off];
#pragma unroll
        for (int s = 1; s < 8; ++s) {
            const float4 f = *(const float4*)&s0[(long)s * partStride + off];
            acc.x += f.x; acc.y += f.y; acc.z += f.z; acc.w += f.w;
        }
        ushort4 v;
        v.x = f2bf(acc.x); v.y = f2bf(acc.y); v.z = f2bf(acc.z); v.w = f2bf(acc.w);
        const int chunk = ((kl >> 5) * 4 + (rl >> 4)) * 64 + ((kl >> 3) & 3) * 16 + (rl & 15);
        *(ushort4*)&dst[chunk * 8 + (kl & 7)] = v;
    }
}

// K-major f32 source [64 k][64 m] -> fragment-major LDS (scatter; verified).
__device__ inline void stage_km64(const float* __restrict__ src, long ld,
                                  u16* __restrict__ dst, int tid) {
#pragma unroll
    for (int it = 0; it < 4; ++it) {
        const int flat = (it * 256 + tid) * 4;
        const int m = flat & 63, k = flat >> 6;
        const float4 f = *(const float4*)&src[(long)k * ld + m];
        const int cb_ = ((k >> 5) * 4 + (m >> 4)) * 64 + ((k & 31) >> 3) * 16 + (m & 15);
        const int j = k & 7;
        dst[(cb_ + 0) * 8 + j] = f2bf(f.x);
        dst[(cb_ + 1) * 8 + j] = f2bf(f.y);
        dst[(cb_ + 2) * 8 + j] = f2bf(f.z);
        dst[(cb_ + 3) * 8 + j] = f2bf(f.w);
    }
}

// 64-tile GEMM body (r13-verbatim): K=256 one burst, one sync.
template <typename TA, typename TB, typename TC,
          bool AKM, bool BKM, bool BSUM8, bool ATOMIC>
__device__ inline void gemm_tile(const TA* __restrict__ A, long lda,
                                 const TB* __restrict__ B, long ldb,
                                 long partStride,
                                 TC* __restrict__ C, long ldc,
                                 int m0, int n0) {
    __shared__ u16 As[16384];   // 32 KB: 4 x 64-k fragment blocks
    __shared__ u16 Bs[16384];
    const int tid = threadIdx.x, lane = tid & 63, w = tid >> 6;
    const int IA = (w & 1) * 2, JB = (w >> 1) * 2;
    floatx4 acc[2][2] = {};

#pragma unroll
    for (int kb = 0; kb < 4; ++kb) {
        if (AKM) stage_km64((const float*)A + (long)(kb * 64) * lda, lda, As + kb * 4096, tid);
        else     stage64(A + kb * 64, lda, As + kb * 4096, tid);
    }
#pragma unroll
    for (int kb = 0; kb < 4; ++kb) {
        if (BSUM8)    stage64_sum8((const float*)B + kb * 64, ldb, partStride, Bs + kb * 4096, tid);
        else if (BKM) stage_km64((const float*)B + (long)(kb * 64) * ldb, ldb, Bs + kb * 4096, tid);
        else          stage64(B + kb * 64, ldb, Bs + kb * 4096, tid);
    }
    __syncthreads();

#pragma unroll
    for (int kb = 0; kb < 4; ++kb)
#pragma unroll
        for (int s = 0; s < 2; ++s) {
            short8 af[2], bfr[2];
#pragma unroll
            for (int i = 0; i < 2; ++i)
                af[i] = *(const short8*)&As[kb * 4096 + ((s * 4 + IA + i) * 64 + lane) * 8];
#pragma unroll
            for (int j = 0; j < 2; ++j)
                bfr[j] = *(const short8*)&Bs[kb * 4096 + ((s * 4 + JB + j) * 64 + lane) * 8];
#pragma unroll
            for (int i = 0; i < 2; ++i)
#pragma unroll
                for (int j = 0; j < 2; ++j)
                    acc[i][j] = __builtin_amdgcn_mfma_f32_16x16x32_bf16(af[i], bfr[j], acc[i][j], 0, 0, 0);
        }

    const int rb = (lane >> 4) * 4, col = lane & 15;
#pragma unroll
    for (int i = 0; i < 2; ++i)
#pragma unroll
        for (int j = 0; j < 2; ++j)
#pragma unroll
            for (int r = 0; r < 4; ++r) {
                const int gm = m0 + (IA + i) * 16 + rb + r;
                const int gn = n0 + (JB + j) * 16 + col;
                TC* p = &C[(long)gm * ldc + gn];
                if (sizeof(TC) == 2) *(u16*)p = f2bf(acc[i][j][r]);
                else if (ATOMIC) atomicAdd((float*)p, acc[i][j][r]);
                else *(float*)p = acc[i][j][r];
            }
}

// ---------------- gram: 128x128 tile ----------------------------------------
// K-major f32 [64 k][128 m] -> 128-row fragment-major block (8192 u16 = 16 KB).
// Element (m,k): lane=((k&31)>>3)*16+(m&15), chunk=((k>>5)*8+(m>>4))*64+lane.
__device__ inline void stage_km128(const float* __restrict__ src, long ld,
                                   u16* __restrict__ dst, int tid) {
#pragma unroll
    for (int it = 0; it < 8; ++it) {
        const int flat = (it * 256 + tid) * 4;
        const int m = flat & 127, k = flat >> 7;
        const float4 f = *(const float4*)&src[(long)k * ld + m];
        const int cb_ = ((k >> 5) * 8 + (m >> 4)) * 64 + ((k & 31) >> 3) * 16 + (m & 15);
        const int j = k & 7;
        dst[(cb_ + 0) * 8 + j] = f2bf(f.x);
        dst[(cb_ + 1) * 8 + j] = f2bf(f.y);
        dst[(cb_ + 2) * 8 + j] = f2bf(f.z);
        dst[(cb_ + 3) * 8 + j] = f2bf(f.w);
    }
}

// Gp[split][bq][f][h] = sum_{u in split} x[b][u][qf] * x[b][u][qh]
// 128x128 tile, two K=128 bursts (64 MFMA/wave/burst), non-atomic.
// Also zeroes this block's 8KB slice of Wt (256 blocks x 2048 floats = 2 MB).
__global__ __launch_bounds__(256) void k_gram(const float* __restrict__ x,
                                              float* __restrict__ Gp,
                                              float* __restrict__ Wt) {
    __shared__ u16 As[16384];   // 32 KB: 2 x (128m x 64k) fragment blocks
    __shared__ u16 Bs[16384];
    const int tl = blockIdx.x, bq = blockIdx.y, split = blockIdx.z;
    const int tm = tl >> 1, tn = tl & 1;
    const int b = bq >> 2, q = bq & 3;
    const int tid = threadIdx.x, lane = tid & 63, w = tid >> 6;
    const int IA2 = (w & 1), JB2 = (w >> 1);     // wave's 64x64 quadrant

    {   // zero Wt: 256 blocks x 2048 floats
        const int bl = tl + 4 * bq + 32 * split;
        float4 zero = {0.f, 0.f, 0.f, 0.f};
        float4* wz = (float4*)(Wt + (long)bl * 2048) + tid;
        wz[0] = zero; wz[256] = zero;
    }

    const float* base = x + (long)b * 2097152 + (long)split * 256 * 1024 + q * 256;
    const float* A = base + tm * 128;    // [k=u][m=f], ld 1024
    const float* B = base + tn * 128;
    floatx4 acc[4][4] = {};

#pragma unroll
    for (int burst = 0; burst < 2; ++burst) {
        if (burst) __syncthreads();
#pragma unroll
        for (int kb = 0; kb < 2; ++kb) {
            const long kk = burst * 128 + kb * 64;
            stage_km128(A + kk * 1024, 1024, As + kb * 8192, tid);
            stage_km128(B + kk * 1024, 1024, Bs + kb * 8192, tid);
        }
        __syncthreads();
#pragma unroll
        for (int kb = 0; kb < 2; ++kb)
#pragma unroll
            for (int s = 0; s < 2; ++s) {
                short8 af[4], bfr[4];
#pragma unroll
                for (int i = 0; i < 4; ++i)
                    af[i] = *(const short8*)&As[kb * 8192 + ((s * 8 + IA2 * 4 + i) * 64 + lane) * 8];
#pragma unroll
                for (int j = 0; j < 4; ++j)
                    bfr[j] = *(const short8*)&Bs[kb * 8192 + ((s * 8 + JB2 * 4 + j) * 64 + lane) * 8];
#pragma unroll
                for (int i = 0; i < 4; ++i)
#pragma unroll
                    for (int j = 0; j < 4; ++j)
                        acc[i][j] = __builtin_amdgcn_mfma_f32_16x16x32_bf16(af[i], bfr[j], acc[i][j], 0, 0, 0);
            }
    }

    float* C = Gp + (long)(split * 8 + bq) * 65536;
    const int rb = (lane >> 4) * 4, col = lane & 15;
#pragma unroll
    for (int i = 0; i < 4; ++i)
#pragma unroll
        for (int j = 0; j < 4; ++j)
#pragma unroll
            for (int r = 0; r < 4; ++r) {
                const int gm = tm * 128 + IA2 * 64 + i * 16 + rb + r;
                const int gn = tn * 128 + JB2 * 64 + j * 16 + col;
                C[(long)gm * 256 + gn] = acc[i][j][r];
            }
}

// 2a: Tt[ba][g][q*256+f] = sum_h comb[a][q*256+h][g] * (sum_s Gp[s][bq])[f][h]
__global__ __launch_bounds__(256) void k_2a(const float* __restrict__ comb,
                                            const float* __restrict__ Gp,
                                            u16* __restrict__ Tt) {
    const int tile = blockIdx.x, i = blockIdx.y;     // i = ba*4+q
    const int tm = tile >> 2, tn = tile & 3;
    const int q = i & 3, ba = i >> 2, b = ba >> 2, a = ba & 3;
    gemm_tile<float, float, u16, true, false, true, false>(
        comb + (long)a * 262144 + (long)q * 256 * 256 + tm * 64, 256,
        Gp + (long)(b * 4 + q) * 65536 + (long)tn * 64 * 256, 256,
        (long)8 * 65536,
        Tt + (long)ba * 262144, 1024,
        tm * 64, q * 256 + tn * 64);
}

// 2b: Wt[ba][g][e] += sum_{k in split} Tt[ba][g][k] * qw[a][e][k]
__global__ __launch_bounds__(256) void k_2b(const u16* __restrict__ Tt,
                                            const float* __restrict__ qw,
                                            float* __restrict__ Wt) {
    const int tile = blockIdx.x, ba = blockIdx.y, split = blockIdx.z;
    const int tm = tile >> 2, tn = tile & 3;
    const int a = ba & 3;
    gemm_tile<u16, float, float, false, false, false, true>(
        Tt + (long)ba * 262144 + (long)tm * 64 * 1024 + split * 256, 1024,
        qw + (long)a * 262144 + (long)tn * 64 * 1024 + split * 256, 1024, 0,
        Wt + (long)ba * 65536, 256,
        tm * 64, tn * 64);
}

// out: out[b][t][a*256+g] = sum_e x[b][t][a*256+e] * Wt[ba][g][e]
__global__ __launch_bounds__(256) void k_3(const float* __restrict__ x,
                                           const float* __restrict__ Wt,
                                           float* __restrict__ out) {
    const int tl = blockIdx.x, ba = blockIdx.y;      // tl: tm 0..31, tn 0..3
    const int tm = tl >> 2, tn = tl & 3;
    const int b = ba >> 2, a = ba & 3;
    gemm_tile<float, float, float, false, false, false, false>(
        x + (long)b * 2097152 + (long)tm * 64 * 1024 + a * 256, 1024,
        Wt + (long)ba * 65536 + (long)tn * 64 * 256, 256, 0,
        out + (long)b * 2097152 + a * 256, 1024,
        tm * 64, tn * 64);
}

extern "C" void kernel_launch(void* const* d_in, const int* in_sizes, int n_in,
                              void* d_out, int out_size, void* d_ws, size_t ws_size,
                              hipStream_t stream) {
    const float* x    = (const float*)d_in[0];   // [2,2048,1024]
    const float* qw   = (const float*)d_in[1];   // [4,256,1024]
    const float* comb = (const float*)d_in[2];   // [4,1024,256]
    float* out = (float*)d_out;

    char* ws = (char*)d_ws;
    float* Gp = (float*)(ws);                    // 16 MB [8 split][8 bq][256x256]
    float* Wt = (float*)(ws + (16u << 20));      // 2 MB  [8][256][256]  Wt[g][e]
    u16*   Tt = (u16*)  (ws + (18u << 20));      // 4 MB  [8][256][1024] Tt[g][qf] bf16

    k_gram<<<dim3(4, 8, 8),  256, 0, stream>>>(x, Gp, Wt);
    k_2a  <<<dim3(16, 32),   256, 0, stream>>>(comb, Gp, Tt);
    k_2b  <<<dim3(16, 8, 4), 256, 0, stream>>>(Tt, qw, Wt);
    k_3   <<<dim3(128, 8),   256, 0, stream>>>(x, Wt, out);
}